// Round 9
// baseline (209.703 us; speedup 1.0000x reference)
//
#include <hip/hip_runtime.h>
#include <hip/hip_bf16.h>

#define Bv 4
#define Tv 2048
#define Ev 1024
#define Hv 16
#define Sv 64

typedef __attribute__((ext_vector_type(8))) short bf16x8;
typedef __attribute__((ext_vector_type(4))) float f32x4;
typedef __attribute__((ext_vector_type(16))) float f32x16;

__device__ __forceinline__ ushort f2bf(float f) {
    unsigned u = __float_as_uint(f);
    u = (u + 0x7FFFu + ((u >> 16) & 1u)) >> 16;
    return (ushort)u;
}
// RNE pack via v_cvt_pk_bf16_f32 (header lowers to HW instr on gfx950)
__device__ __forceinline__ unsigned pkrn(float a, float b) {
    __hip_bfloat162 t = __float22bfloat162_rn(make_float2(a, b));
    unsigned r; __builtin_memcpy(&r, &t, 4); return r;
}
// truncation pack, 1 VALU op (v_perm_b32): {lo=a_trunc, hi=b_trunc}
__device__ __forceinline__ unsigned pktr(float a, float b) {
    return __builtin_amdgcn_perm(__float_as_uint(b), __float_as_uint(a), 0x07060302u);
}

// async global->LDS, 16B per lane (global_load_lds_dwordx4)
__device__ __forceinline__ void async16(void* lds, const void* g) {
    __builtin_amdgcn_global_load_lds(
        (const __attribute__((address_space(1))) unsigned int*)g,
        (__attribute__((address_space(3))) unsigned int*)lds, 16, 0, 0);
}

// ---------------------------------------------------------------------------
// Kernel 1: QKV projection + Wp cast (fused; unchanged from R8).
// ---------------------------------------------------------------------------
__global__ __launch_bounds__(192) void qkv_kernel(
    const float* __restrict__ x,
    const float* __restrict__ Wq, const float* __restrict__ Wk,
    const float* __restrict__ Wv, const float* __restrict__ Wp,
    ushort* __restrict__ Wpb,
    ushort* __restrict__ Q, ushort* __restrict__ K, ushort* __restrict__ Vt)
{
    // ---- fused Wp cast blocks (683 x 192 x 8 floats >= 1M, guarded) ----
    if (blockIdx.x >= 2048) {
        size_t i = ((size_t)(blockIdx.x - 2048) * 192 + threadIdx.x) * 8;
        if (i < (size_t)Ev * Ev) {
            float4 v0 = *(const float4*)(Wp + i);
            float4 v1 = *(const float4*)(Wp + i + 4);
            uint4 o = {pkrn(v0.x, v0.y), pkrn(v0.z, v0.w),
                       pkrn(v1.x, v1.y), pkrn(v1.z, v1.w)};
            *(uint4*)(Wpb + i) = o;
        }
        return;
    }

    __shared__ float xs[16 * 256];   // [token][4 heads * 64], granule-swizzled

    const int tid  = threadIdx.x;
    const int wave = tid >> 6;        // 0=Q 1=K 2=V
    const int lane = tid & 63;
    const int m    = lane & 15;
    const int quad = lane >> 4;

    const int tt = blockIdx.x >> 2;   // 0..511 token tile
    const int hg = blockIdx.x & 3;    // head group
    const int g0 = tt * 16;
    const int b  = g0 >> 11;
    const int t0 = g0 & 2047;

    // stage x tile: chunk c (16B) -> xs linear; source granule pre-swizzled
    #pragma unroll
    for (int pass = 0; pass < 6; ++pass) {
        int c = pass * 192 + tid;
        if (c < 1024) {
            int tok  = c >> 6;
            int gsrc = (c & 63) ^ (tok & 7);
            async16(&xs[c * 4],
                    x + (size_t)(g0 + tok) * Ev + hg * 256 + gsrc * 4);
        }
    }

    // self-cast weight fragments (fp32 -> bf16, scale folded for Q)
    const float* Wsel = (wave == 0) ? Wq : ((wave == 1) ? Wk : Wv);
    const float wscale = (wave == 0) ? 0.03125f * 1.4426950408889634f : 1.0f;
    bf16x8 wf[4][2];
    #pragma unroll
    for (int ot = 0; ot < 4; ++ot)
        #pragma unroll
        for (int ks = 0; ks < 2; ++ks) {
            const float* ws = &Wsel[(ot * 16 + m) * 64 + ks * 32 + quad * 8];
            float4 w0 = *(const float4*)ws;
            float4 w1 = *(const float4*)(ws + 4);
            unsigned pk[4];
            pk[0] = pkrn(w0.x * wscale, w0.y * wscale);
            pk[1] = pkrn(w0.z * wscale, w0.w * wscale);
            pk[2] = pkrn(w1.x * wscale, w1.y * wscale);
            pk[3] = pkrn(w1.z * wscale, w1.w * wscale);
            wf[ot][ks] = *(bf16x8*)pk;
        }

    __syncthreads();   // x tile resident

    #pragma unroll
    for (int hi = 0; hi < 4; ++hi) {
        const int h  = hg * 4 + hi;
        const int bh = b * Hv + h;

        // xf from LDS: granule gc = hi*16 + ks*8 + quad*2, phys = gc^(m&7)
        bf16x8 xf[2];
        #pragma unroll
        for (int ks = 0; ks < 2; ++ks) {
            int gc = hi * 16 + ks * 8 + quad * 2;
            float4 v0 = *(const float4*)&xs[(m * 64 + ( gc      ^ (m & 7))) * 4];
            float4 v1 = *(const float4*)&xs[(m * 64 + ((gc + 1) ^ (m & 7))) * 4];
            unsigned pk[4];
            pk[0] = pkrn(v0.x, v0.y); pk[1] = pkrn(v0.z, v0.w);
            pk[2] = pkrn(v1.x, v1.y); pk[3] = pkrn(v1.z, v1.w);
            xf[ks] = *(bf16x8*)pk;
        }

        f32x4 acc[4];
        #pragma unroll
        for (int ot = 0; ot < 4; ++ot) acc[ot] = (f32x4){0.f, 0.f, 0.f, 0.f};

        if (wave < 2) {
            // D[t][o]: col = o (contiguous), row = t-local = quad*4 + r
            #pragma unroll
            for (int ks = 0; ks < 2; ++ks)
                #pragma unroll
                for (int ot = 0; ot < 4; ++ot)
                    acc[ot] = __builtin_amdgcn_mfma_f32_16x16x32_bf16(
                        xf[ks], wf[ot][ks], acc[ot], 0, 0, 0);
            ushort* dst = ((wave == 0) ? Q : K) + ((size_t)bh * Tv + t0) * Sv;
            #pragma unroll
            for (int ot = 0; ot < 4; ++ot)
                #pragma unroll
                for (int r = 0; r < 4; ++r)
                    dst[(quad * 4 + r) * Sv + ot * 16 + m]
                        = (ushort)pkrn(acc[ot][r], acc[ot][r]);
        } else {
            #pragma unroll
            for (int ks = 0; ks < 2; ++ks)
                #pragma unroll
                for (int st = 0; st < 4; ++st)
                    acc[st] = __builtin_amdgcn_mfma_f32_16x16x32_bf16(
                        xf[ks], wf[st][ks], acc[st], 0, 0, 0);
            ushort* vr = Vt + ((size_t)bh * Sv + m) * Tv + t0 + quad * 4;
            #pragma unroll
            for (int st = 0; st < 4; ++st) {
                uint2 w = {pkrn(acc[st][0], acc[st][1]), pkrn(acc[st][2], acc[st][3])};
                *(uint2*)(vr + (size_t)st * 16 * Tv) = w;
            }
        }
    }
}

// ---------------------------------------------------------------------------
// Kernel 2: flash attention v15 — v13 math + 3-BUFFER global_load_lds RING.
// v13 reg-staged because a 2-buffer global_load_lds pipeline self-conflicts
// (t+2 loads target the buffer being read). A 3-slot ring fixes that: iter t
// issues global_load_lds tile t+2 -> buf[(t+2)%3] (idle since its read at
// t-1, barrier-protected), computes buf[t%3], ONE barrier. Same 1-phase load
// cover as v13, but the ds_write leg is GONE: DS instrs/wave-iter 20->16
// (-20% on the most-loaded pipe), staging VGPRs -16, addressing simpler.
// LDS 50KB; 2 blocks/CU unchanged (grid-limited). Source pre-swizzled +
// linear dest per rule #21 (unchanged pattern).
// ---------------------------------------------------------------------------
__global__ __launch_bounds__(256, 2) void attn_kernel(
    const ushort* __restrict__ Q, const ushort* __restrict__ K,
    const ushort* __restrict__ Vt, ushort* __restrict__ O)
{
    __shared__ ushort kl[3][64 * 64];     // K ring  [key][d]   (swizzled)
    __shared__ ushort vl[3][64 * 64];     // Vt ring [s][key]   (swizzled)
    __shared__ float  ll[4][64];          // per-wave 1/lsum bounce

    const int tid  = threadIdx.x;
    const int wave = tid >> 6;
    const int lane = tid & 63;
    const int r31  = lane & 31;
    const int hi   = lane >> 5;
    const int bh   = blockIdx.x & 63;
    const int q0   = (blockIdx.x >> 6) << 8;   // query tile base (256)

    // Q B-frags: group g covers queries q0 + wave*64 + g*32 + r31,
    // k = ks*16 + hi*8 + j
    const ushort* Qb = Q + ((size_t)bh * Tv + q0 + wave * 64 + r31) * Sv + hi * 8;
    bf16x8 qf[2][4];
    #pragma unroll
    for (int g = 0; g < 2; ++g)
        #pragma unroll
        for (int ks = 0; ks < 4; ++ks)
            qf[g][ks] = *(const bf16x8*)(Qb + (size_t)g * 32 * Sv + ks * 16);

    f32x16 oa[2][2];
    #pragma unroll
    for (int g = 0; g < 2; ++g)
        #pragma unroll
        for (int st = 0; st < 2; ++st)
            #pragma unroll
            for (int r = 0; r < 16; ++r)
                oa[g][st][r] = 0.f;
    float lsum[2] = {0.f, 0.f};

    const ushort* Kb = K  + (size_t)bh * Tv * Sv;
    const ushort* Vb = Vt + (size_t)bh * Sv * Tv;

    // staging geometry (swizzled): chunk c -> row=c>>3, phys cg=c&7,
    // source col-group = (c&7) ^ (row&7)
    const int r0 = tid >> 3,         cg0 = (tid & 7) ^ (r0 & 7);
    const int r1 = (256 + tid) >> 3, cg1 = ((256 + tid) & 7) ^ (r1 & 7);
    const size_t koff0 = (size_t)r0 * Sv + cg0 * 8;
    const size_t koff1 = (size_t)r1 * Sv + cg1 * 8;
    const size_t voff0 = (size_t)r0 * Tv + cg0 * 8;
    const size_t voff1 = (size_t)r1 * Tv + cg1 * 8;
    const int swz = r31 & 7;

    // softmax + PV for one 32-query group (everything statically indexed)
    auto softpv = [&](const f32x16& sv, float& ls, f32x16* oag, int kp,
                      const bf16x8* vf) {
        float p[8];
        #pragma unroll
        for (int j = 0; j < 8; ++j)
            p[j] = __builtin_amdgcn_exp2f(sv[kp * 8 + j]);
        ls += ((p[0] + p[1]) + (p[2] + p[3]))
            + ((p[4] + p[5]) + (p[6] + p[7]));
        unsigned d0 = pktr(p[0], p[1]);
        unsigned d1 = pktr(p[2], p[3]);
        unsigned d2 = pktr(p[4], p[5]);
        unsigned d3 = pktr(p[6], p[7]);
        asm volatile("v_permlane32_swap_b32 %0, %1" : "+v"(d0), "+v"(d2));
        asm volatile("v_permlane32_swap_b32 %0, %1" : "+v"(d1), "+v"(d3));
        unsigned pw[4] = {d0, d1, d2, d3};
        bf16x8 pf = *(bf16x8*)pw;
        #pragma unroll
        for (int st = 0; st < 2; ++st)
            oag[st] = __builtin_amdgcn_mfma_f32_32x32x16_bf16(
                pf, vf[st], oag[st], 0, 0, 0);
    };

    // issue loads for 64-key tile t into ring slot s
    auto stage = [&](int t, int s) {
        const size_t kk = (size_t)t * 64;
        async16(&kl[s][(size_t)tid * 8],         Kb + kk * Sv + koff0);
        async16(&kl[s][((size_t)tid + 256) * 8], Kb + kk * Sv + koff1);
        async16(&vl[s][(size_t)tid * 8],         Vb + kk + voff0);
        async16(&vl[s][((size_t)tid + 256) * 8], Vb + kk + voff1);
    };

    // prologue: tiles 0,1 -> slots 0,1
    stage(0, 0);
    stage(1, 1);
    __syncthreads();   // vmcnt(0): both resident

    int cur = 0;       // slot holding tile t (wave-uniform)
    for (int t = 0; t < 32; ++t) {
        // issue tile t+2 into slot (cur+2)%3 == (cur-1+3)%3 — idle since
        // its read finished at iter t-1 (barrier-protected)
        if (t < 30) stage(t + 2, (cur == 0) ? 2 : cur - 1);

        #pragma unroll
        for (int kt = 0; kt < 2; ++kt) {
            // kf loaded ONCE, reused for both query groups
            bf16x8 kf[4];
            #pragma unroll
            for (int ks = 0; ks < 4; ++ks)
                kf[ks] = *(const bf16x8*)
                    &kl[cur][(kt * 32 + r31) * 64 + (((ks * 2 + hi) ^ swz) * 8)];

            // S^T = K·Q^T (32x32x16): D col = q = r31,
            // row = key_local = (r&3) + 4*hi + 8*(r>>2)
            f32x16 s0, s1;
            #pragma unroll
            for (int r = 0; r < 16; ++r) { s0[r] = 0.f; s1[r] = 0.f; }
            #pragma unroll
            for (int ks = 0; ks < 4; ++ks)
                s0 = __builtin_amdgcn_mfma_f32_32x32x16_bf16(
                    kf[ks], qf[0][ks], s0, 0, 0, 0);
            #pragma unroll
            for (int ks = 0; ks < 4; ++ks)
                s1 = __builtin_amdgcn_mfma_f32_32x32x16_bf16(
                    kf[ks], qf[1][ks], s1, 0, 0, 0);

            #pragma unroll
            for (int kp = 0; kp < 2; ++kp) {
                const int kc = (kt * 2 + kp) * 2 + hi;  // V col chunk
                bf16x8 vf[2];
                #pragma unroll
                for (int st = 0; st < 2; ++st)
                    vf[st] = *(const bf16x8*)
                        &vl[cur][(st * 32 + r31) * 64 + ((kc ^ swz) * 8)];
                softpv(s0, lsum[0], oa[0], kp, vf);
                softpv(s1, lsum[1], oa[1], kp, vf);
            }
        }

        // ONE barrier per iter: drains this iter's issued loads (they had
        // the full compute phase above) and closes the read window on cur.
        __syncthreads();
        cur = (cur == 2) ? 0 : cur + 1;
    }

    // row sum: halves hold disjoint key sets for the same q -> one xor-32
    lsum[0] += __shfl_xor(lsum[0], 32, 64);
    lsum[1] += __shfl_xor(lsum[1], 32, 64);
    if (hi == 0) {
        ll[wave][r31]      = 1.0f / lsum[0];
        ll[wave][32 + r31] = 1.0f / lsum[1];
    }

    const int b = bh >> 4, h = bh & 15;
    #pragma unroll
    for (int g = 0; g < 2; ++g) {
        float sc[16];
        #pragma unroll
        for (int r = 0; r < 16; ++r)
            sc[r] = ll[wave][g * 32 + (r & 3) + 4 * hi + 8 * (r >> 2)];
        #pragma unroll
        for (int st = 0; st < 2; ++st)
            #pragma unroll
            for (int r = 0; r < 16; ++r) {
                const int q = (r & 3) + 4 * hi + 8 * (r >> 2);
                O[((size_t)(b * Tv + q0 + wave * 64 + g * 32 + q)) * Ev
                  + h * Sv + st * 32 + r31] = f2bf(oa[g][st][r] * sc[r]);
            }
    }
}

// ---------------------------------------------------------------------------
// Kernel 3: output projection — R8 reg-staged double-buffer (unchanged).
// ---------------------------------------------------------------------------
__global__ __launch_bounds__(256) void proj_kernel(
    const ushort* __restrict__ A, const ushort* __restrict__ Bw,
    const float* __restrict__ bp, float* __restrict__ C)
{
    __shared__ ushort Asm[2][128 * 32];
    __shared__ ushort Bsm[2][128 * 32];
    const int tid  = threadIdx.x;
    const int wave = tid >> 6;
    const int lane = tid & 63;
    const int m    = lane & 15;
    const int quad = lane >> 4;
    const int wm   = wave >> 1;
    const int wn   = wave & 1;
    const int m0   = blockIdx.x * 128;
    const int n0   = blockIdx.y * 128;

    f32x4 acc[4][4];
    #pragma unroll
    for (int i = 0; i < 4; ++i)
        #pragma unroll
        for (int j = 0; j < 4; ++j)
            acc[i][j] = (f32x4){0.f, 0.f, 0.f, 0.f};

    const int row0 = tid >> 2,         col0 = (tid & 3) * 8;
    const int row1 = (256 + tid) >> 2, col1 = ((256 + tid) & 3) * 8;

    // prologue: k=0 -> buf0 (via regs); k=32 -> regs
    uint4 a0 = *(const uint4*)&A [(size_t)(m0 + row0) * Ev + col0];
    uint4 a1 = *(const uint4*)&A [(size_t)(m0 + row1) * Ev + col1];
    uint4 b0 = *(const uint4*)&Bw[(size_t)(n0 + row0) * Ev + col0];
    uint4 b1 = *(const uint4*)&Bw[(size_t)(n0 + row1) * Ev + col1];
    *(uint4*)&Asm[0][(size_t)tid * 8]         = a0;
    *(uint4*)&Asm[0][((size_t)tid + 256) * 8] = a1;
    *(uint4*)&Bsm[0][(size_t)tid * 8]         = b0;
    *(uint4*)&Bsm[0][((size_t)tid + 256) * 8] = b1;
    a0 = *(const uint4*)&A [(size_t)(m0 + row0) * Ev + 32 + col0];
    a1 = *(const uint4*)&A [(size_t)(m0 + row1) * Ev + 32 + col1];
    b0 = *(const uint4*)&Bw[(size_t)(n0 + row0) * Ev + 32 + col0];
    b1 = *(const uint4*)&Bw[(size_t)(n0 + row1) * Ev + 32 + col1];
    __syncthreads();

    for (int it = 0; it < 32; ++it) {
        const int cur = it & 1;
        if (it < 31) {
            // stage k-step it+1 from regs into the other buffer
            *(uint4*)&Asm[cur ^ 1][(size_t)tid * 8]         = a0;
            *(uint4*)&Asm[cur ^ 1][((size_t)tid + 256) * 8] = a1;
            *(uint4*)&Bsm[cur ^ 1][(size_t)tid * 8]         = b0;
            *(uint4*)&Bsm[cur ^ 1][((size_t)tid + 256) * 8] = b1;
            // issue k-step it+2 loads; land during the MFMAs below
            int kn = (it + 2) * 32; if (kn >= Ev) kn = 0;  // clamped tail
            a0 = *(const uint4*)&A [(size_t)(m0 + row0) * Ev + kn + col0];
            a1 = *(const uint4*)&A [(size_t)(m0 + row1) * Ev + kn + col1];
            b0 = *(const uint4*)&Bw[(size_t)(n0 + row0) * Ev + kn + col0];
            b1 = *(const uint4*)&Bw[(size_t)(n0 + row1) * Ev + kn + col1];
        }

        bf16x8 af[4], bf[4];
        #pragma unroll
        for (int i = 0; i < 4; ++i)
            af[i] = *(const bf16x8*)&Asm[cur][(wm * 64 + i * 16 + m) * 32 + quad * 8];
        #pragma unroll
        for (int j = 0; j < 4; ++j)
            bf[j] = *(const bf16x8*)&Bsm[cur][(wn * 64 + j * 16 + m) * 32 + quad * 8];
        #pragma unroll
        for (int i = 0; i < 4; ++i)
            #pragma unroll
            for (int j = 0; j < 4; ++j)
                acc[i][j] = __builtin_amdgcn_mfma_f32_16x16x32_bf16(
                    af[i], bf[j], acc[i][j], 0, 0, 0);

        __syncthreads();
    }

    float bbv[4];
    #pragma unroll
    for (int j = 0; j < 4; ++j)
        bbv[j] = bp[n0 + wn * 64 + j * 16 + m];

    #pragma unroll
    for (int i = 0; i < 4; ++i)
        #pragma unroll
        for (int j = 0; j < 4; ++j)
            #pragma unroll
            for (int r = 0; r < 4; ++r)
                C[(size_t)(m0 + wm * 64 + i * 16 + quad * 4 + r) * Ev
                  + n0 + wn * 64 + j * 16 + m] = acc[i][j][r] + bbv[j];
}

// ---------------------------------------------------------------------------
// ws layout (ushort units): Q 8.4M | K 8.4M | Vt 8.4M | O 8.4M | Wpb 1M
// ---------------------------------------------------------------------------
extern "C" void kernel_launch(void* const* d_in, const int* in_sizes, int n_in,
                              void* d_out, int out_size, void* d_ws, size_t ws_size,
                              hipStream_t stream) {
    const float* x  = (const float*)d_in[0];
    const float* Wk = (const float*)d_in[1];
    const float* Wq = (const float*)d_in[2];
    const float* Wv = (const float*)d_in[3];
    const float* Wp = (const float*)d_in[4];
    const float* bp = (const float*)d_in[5];
    float* out = (float*)d_out;

    ushort* Q   = (ushort*)d_ws;
    ushort* K   = Q   + 8388608;
    ushort* Vt  = K   + 8388608;
    ushort* O   = Vt  + 8388608;
    ushort* Wpb = O   + 8388608;

    qkv_kernel<<<2731, 192, 0, stream>>>(x, Wq, Wk, Wv, Wp, Wpb, Q, K, Vt);
    attn_kernel<<<512, 256, 0, stream>>>(Q, K, Vt, O);
    proj_kernel<<<dim3(64, 8), 256, 0, stream>>>(O, Wpb, bp, out);
}

// Round 10
// 207.802 us; speedup vs baseline: 1.0091x; 1.0091x over previous
//
#include <hip/hip_runtime.h>
#include <hip/hip_bf16.h>

#define Bv 4
#define Tv 2048
#define Ev 1024
#define Hv 16
#define Sv 64

typedef __attribute__((ext_vector_type(8))) short bf16x8;
typedef __attribute__((ext_vector_type(4))) float f32x4;
typedef __attribute__((ext_vector_type(16))) float f32x16;

__device__ __forceinline__ ushort f2bf(float f) {
    unsigned u = __float_as_uint(f);
    u = (u + 0x7FFFu + ((u >> 16) & 1u)) >> 16;
    return (ushort)u;
}
// RNE pack via v_cvt_pk_bf16_f32 (header lowers to HW instr on gfx950)
__device__ __forceinline__ unsigned pkrn(float a, float b) {
    __hip_bfloat162 t = __float22bfloat162_rn(make_float2(a, b));
    unsigned r; __builtin_memcpy(&r, &t, 4); return r;
}
// truncation pack, 1 VALU op (v_perm_b32): {lo=a_trunc, hi=b_trunc}
__device__ __forceinline__ unsigned pktr(float a, float b) {
    return __builtin_amdgcn_perm(__float_as_uint(b), __float_as_uint(a), 0x07060302u);
}

// async global->LDS, 16B per lane (global_load_lds_dwordx4)
__device__ __forceinline__ void async16(void* lds, const void* g) {
    __builtin_amdgcn_global_load_lds(
        (const __attribute__((address_space(1))) unsigned int*)g,
        (__attribute__((address_space(3))) unsigned int*)lds, 16, 0, 0);
}

// ---------------------------------------------------------------------------
// Kernel 1: QKV projection + Wp cast (fused; R8 verbatim — measured best).
// ---------------------------------------------------------------------------
__global__ __launch_bounds__(192) void qkv_kernel(
    const float* __restrict__ x,
    const float* __restrict__ Wq, const float* __restrict__ Wk,
    const float* __restrict__ Wv, const float* __restrict__ Wp,
    ushort* __restrict__ Wpb,
    ushort* __restrict__ Q, ushort* __restrict__ K, ushort* __restrict__ Vt)
{
    // ---- fused Wp cast blocks (683 x 192 x 8 floats >= 1M, guarded) ----
    if (blockIdx.x >= 2048) {
        size_t i = ((size_t)(blockIdx.x - 2048) * 192 + threadIdx.x) * 8;
        if (i < (size_t)Ev * Ev) {
            float4 v0 = *(const float4*)(Wp + i);
            float4 v1 = *(const float4*)(Wp + i + 4);
            uint4 o = {pkrn(v0.x, v0.y), pkrn(v0.z, v0.w),
                       pkrn(v1.x, v1.y), pkrn(v1.z, v1.w)};
            *(uint4*)(Wpb + i) = o;
        }
        return;
    }

    __shared__ float xs[16 * 256];   // [token][4 heads * 64], granule-swizzled

    const int tid  = threadIdx.x;
    const int wave = tid >> 6;        // 0=Q 1=K 2=V
    const int lane = tid & 63;
    const int m    = lane & 15;
    const int quad = lane >> 4;

    const int tt = blockIdx.x >> 2;   // 0..511 token tile
    const int hg = blockIdx.x & 3;    // head group
    const int g0 = tt * 16;
    const int b  = g0 >> 11;
    const int t0 = g0 & 2047;

    // stage x tile: chunk c (16B) -> xs linear; source granule pre-swizzled
    #pragma unroll
    for (int pass = 0; pass < 6; ++pass) {
        int c = pass * 192 + tid;
        if (c < 1024) {
            int tok  = c >> 6;
            int gsrc = (c & 63) ^ (tok & 7);
            async16(&xs[c * 4],
                    x + (size_t)(g0 + tok) * Ev + hg * 256 + gsrc * 4);
        }
    }

    // self-cast weight fragments (fp32 -> bf16, scale folded for Q)
    const float* Wsel = (wave == 0) ? Wq : ((wave == 1) ? Wk : Wv);
    const float wscale = (wave == 0) ? 0.03125f * 1.4426950408889634f : 1.0f;
    bf16x8 wf[4][2];
    #pragma unroll
    for (int ot = 0; ot < 4; ++ot)
        #pragma unroll
        for (int ks = 0; ks < 2; ++ks) {
            const float* ws = &Wsel[(ot * 16 + m) * 64 + ks * 32 + quad * 8];
            float4 w0 = *(const float4*)ws;
            float4 w1 = *(const float4*)(ws + 4);
            unsigned pk[4];
            pk[0] = pkrn(w0.x * wscale, w0.y * wscale);
            pk[1] = pkrn(w0.z * wscale, w0.w * wscale);
            pk[2] = pkrn(w1.x * wscale, w1.y * wscale);
            pk[3] = pkrn(w1.z * wscale, w1.w * wscale);
            wf[ot][ks] = *(bf16x8*)pk;
        }

    __syncthreads();   // x tile resident

    #pragma unroll
    for (int hi = 0; hi < 4; ++hi) {
        const int h  = hg * 4 + hi;
        const int bh = b * Hv + h;

        // xf from LDS: granule gc = hi*16 + ks*8 + quad*2, phys = gc^(m&7)
        bf16x8 xf[2];
        #pragma unroll
        for (int ks = 0; ks < 2; ++ks) {
            int gc = hi * 16 + ks * 8 + quad * 2;
            float4 v0 = *(const float4*)&xs[(m * 64 + ( gc      ^ (m & 7))) * 4];
            float4 v1 = *(const float4*)&xs[(m * 64 + ((gc + 1) ^ (m & 7))) * 4];
            unsigned pk[4];
            pk[0] = pkrn(v0.x, v0.y); pk[1] = pkrn(v0.z, v0.w);
            pk[2] = pkrn(v1.x, v1.y); pk[3] = pkrn(v1.z, v1.w);
            xf[ks] = *(bf16x8*)pk;
        }

        f32x4 acc[4];
        #pragma unroll
        for (int ot = 0; ot < 4; ++ot) acc[ot] = (f32x4){0.f, 0.f, 0.f, 0.f};

        if (wave < 2) {
            // D[t][o]: col = o (contiguous), row = t-local = quad*4 + r
            #pragma unroll
            for (int ks = 0; ks < 2; ++ks)
                #pragma unroll
                for (int ot = 0; ot < 4; ++ot)
                    acc[ot] = __builtin_amdgcn_mfma_f32_16x16x32_bf16(
                        xf[ks], wf[ot][ks], acc[ot], 0, 0, 0);
            ushort* dst = ((wave == 0) ? Q : K) + ((size_t)bh * Tv + t0) * Sv;
            #pragma unroll
            for (int ot = 0; ot < 4; ++ot)
                #pragma unroll
                for (int r = 0; r < 4; ++r)
                    dst[(quad * 4 + r) * Sv + ot * 16 + m]
                        = (ushort)pkrn(acc[ot][r], acc[ot][r]);
        } else {
            #pragma unroll
            for (int ks = 0; ks < 2; ++ks)
                #pragma unroll
                for (int st = 0; st < 4; ++st)
                    acc[st] = __builtin_amdgcn_mfma_f32_16x16x32_bf16(
                        xf[ks], wf[st][ks], acc[st], 0, 0, 0);
            ushort* vr = Vt + ((size_t)bh * Sv + m) * Tv + t0 + quad * 4;
            #pragma unroll
            for (int st = 0; st < 4; ++st) {
                uint2 w = {pkrn(acc[st][0], acc[st][1]), pkrn(acc[st][2], acc[st][3])};
                *(uint2*)(vr + (size_t)st * 16 * Tv) = w;
            }
        }
    }
}

// ---------------------------------------------------------------------------
// Kernel 2: flash attention v13 (R8 verbatim — measured best 76.5us).
// R9's gload_lds ring regressed (84.8): barrier must drain vmcnt(0) for LDS
// visibility with only 1 phase of cover, while reg-staging's loads target
// VGPRs (no visibility requirement) so the barrier only waits lgkmcnt and
// the loads' waitcnt sits at next iter's ds_write — ~2 phases of cover.
// ---------------------------------------------------------------------------
__global__ __launch_bounds__(256, 2) void attn_kernel(
    const ushort* __restrict__ Q, const ushort* __restrict__ K,
    const ushort* __restrict__ Vt, ushort* __restrict__ O)
{
    __shared__ ushort kl[2][64 * 64];     // K tile  [key][d]   (swizzled)
    __shared__ ushort vl[2][64 * 64];     // Vt tile [s][key]   (swizzled)
    __shared__ float  ll[4][64];          // per-wave 1/lsum bounce

    const int tid  = threadIdx.x;
    const int wave = tid >> 6;
    const int lane = tid & 63;
    const int r31  = lane & 31;
    const int hi   = lane >> 5;
    const int bh   = blockIdx.x & 63;
    const int q0   = (blockIdx.x >> 6) << 8;   // query tile base (256)

    // Q B-frags: group g covers queries q0 + wave*64 + g*32 + r31,
    // k = ks*16 + hi*8 + j
    const ushort* Qb = Q + ((size_t)bh * Tv + q0 + wave * 64 + r31) * Sv + hi * 8;
    bf16x8 qf[2][4];
    #pragma unroll
    for (int g = 0; g < 2; ++g)
        #pragma unroll
        for (int ks = 0; ks < 4; ++ks)
            qf[g][ks] = *(const bf16x8*)(Qb + (size_t)g * 32 * Sv + ks * 16);

    f32x16 oa[2][2];
    #pragma unroll
    for (int g = 0; g < 2; ++g)
        #pragma unroll
        for (int st = 0; st < 2; ++st)
            #pragma unroll
            for (int r = 0; r < 16; ++r)
                oa[g][st][r] = 0.f;
    float lsum[2] = {0.f, 0.f};

    const ushort* Kb = K  + (size_t)bh * Tv * Sv;
    const ushort* Vb = Vt + (size_t)bh * Sv * Tv;

    // staging geometry (swizzled): chunk c -> row=c>>3, phys cg=c&7,
    // source col-group = (c&7) ^ (row&7)
    const int r0 = tid >> 3,         cg0 = (tid & 7) ^ (r0 & 7);
    const int r1 = (256 + tid) >> 3, cg1 = ((256 + tid) & 7) ^ (r1 & 7);
    const size_t koff0 = (size_t)r0 * Sv + cg0 * 8;
    const size_t koff1 = (size_t)r1 * Sv + cg1 * 8;
    const size_t voff0 = (size_t)r0 * Tv + cg0 * 8;
    const size_t voff1 = (size_t)r1 * Tv + cg1 * 8;
    const int swz = r31 & 7;

    // softmax + PV for one 32-query group (everything statically indexed)
    auto softpv = [&](const f32x16& sv, float& ls, f32x16* oag, int kp,
                      const bf16x8* vf) {
        float p[8];
        #pragma unroll
        for (int j = 0; j < 8; ++j)
            p[j] = __builtin_amdgcn_exp2f(sv[kp * 8 + j]);
        ls += ((p[0] + p[1]) + (p[2] + p[3]))
            + ((p[4] + p[5]) + (p[6] + p[7]));
        unsigned d0 = pktr(p[0], p[1]);
        unsigned d1 = pktr(p[2], p[3]);
        unsigned d2 = pktr(p[4], p[5]);
        unsigned d3 = pktr(p[6], p[7]);
        asm volatile("v_permlane32_swap_b32 %0, %1" : "+v"(d0), "+v"(d2));
        asm volatile("v_permlane32_swap_b32 %0, %1" : "+v"(d1), "+v"(d3));
        unsigned pw[4] = {d0, d1, d2, d3};
        bf16x8 pf = *(bf16x8*)pw;
        #pragma unroll
        for (int st = 0; st < 2; ++st)
            oag[st] = __builtin_amdgcn_mfma_f32_32x32x16_bf16(
                pf, vf[st], oag[st], 0, 0, 0);
    };

    // prologue: tile 0 -> buf0 (via regs), tile 1 -> regs
    uint4 rk0 = *(const uint4*)(Kb + koff0);
    uint4 rk1 = *(const uint4*)(Kb + koff1);
    uint4 rv0 = *(const uint4*)(Vb + voff0);
    uint4 rv1 = *(const uint4*)(Vb + voff1);
    *(uint4*)&kl[0][(size_t)tid * 8]         = rk0;
    *(uint4*)&kl[0][((size_t)tid + 256) * 8] = rk1;
    *(uint4*)&vl[0][(size_t)tid * 8]         = rv0;
    *(uint4*)&vl[0][((size_t)tid + 256) * 8] = rv1;
    rk0 = *(const uint4*)(Kb + (size_t)64 * Sv + koff0);
    rk1 = *(const uint4*)(Kb + (size_t)64 * Sv + koff1);
    rv0 = *(const uint4*)(Vb + 64 + voff0);
    rv1 = *(const uint4*)(Vb + 64 + voff1);
    __syncthreads();

    for (int k0 = 0; k0 < Tv; k0 += 64) {
        const int cur = (k0 >> 6) & 1;

        // stage tile t+1 from regs into the other buffer
        *(uint4*)&kl[cur ^ 1][(size_t)tid * 8]         = rk0;
        *(uint4*)&kl[cur ^ 1][((size_t)tid + 256) * 8] = rk1;
        *(uint4*)&vl[cur ^ 1][(size_t)tid * 8]         = rv0;
        *(uint4*)&vl[cur ^ 1][((size_t)tid + 256) * 8] = rv1;

        // issue tile t+2 loads; they land during the compute below
        int kn = k0 + 128; if (kn >= Tv) kn = 0;   // clamped dummy on tail
        rk0 = *(const uint4*)(Kb + (size_t)kn * Sv + koff0);
        rk1 = *(const uint4*)(Kb + (size_t)kn * Sv + koff1);
        rv0 = *(const uint4*)(Vb + kn + voff0);
        rv1 = *(const uint4*)(Vb + kn + voff1);

        #pragma unroll
        for (int kt = 0; kt < 2; ++kt) {
            // kf loaded ONCE, reused for both query groups
            bf16x8 kf[4];
            #pragma unroll
            for (int ks = 0; ks < 4; ++ks)
                kf[ks] = *(const bf16x8*)
                    &kl[cur][(kt * 32 + r31) * 64 + (((ks * 2 + hi) ^ swz) * 8)];

            // S^T = K·Q^T (32x32x16): D col = q = r31,
            // row = key_local = (r&3) + 4*hi + 8*(r>>2)
            f32x16 s0, s1;
            #pragma unroll
            for (int r = 0; r < 16; ++r) { s0[r] = 0.f; s1[r] = 0.f; }
            #pragma unroll
            for (int ks = 0; ks < 4; ++ks)
                s0 = __builtin_amdgcn_mfma_f32_32x32x16_bf16(
                    kf[ks], qf[0][ks], s0, 0, 0, 0);
            #pragma unroll
            for (int ks = 0; ks < 4; ++ks)
                s1 = __builtin_amdgcn_mfma_f32_32x32x16_bf16(
                    kf[ks], qf[1][ks], s1, 0, 0, 0);

            #pragma unroll
            for (int kp = 0; kp < 2; ++kp) {
                const int kc = (kt * 2 + kp) * 2 + hi;  // V col chunk
                bf16x8 vf[2];
                #pragma unroll
                for (int st = 0; st < 2; ++st)
                    vf[st] = *(const bf16x8*)
                        &vl[cur][(st * 32 + r31) * 64 + ((kc ^ swz) * 8)];
                softpv(s0, lsum[0], oa[0], kp, vf);
                softpv(s1, lsum[1], oa[1], kp, vf);
            }
        }

        // ONE barrier per iter: publishes this iter's ds_writes (lgkmcnt),
        // closes the read window on buf[cur], drains the t+2 loads (which
        // just had the whole compute phase to land).
        __syncthreads();
    }

    // row sum: halves hold disjoint key sets for the same q -> one xor-32
    lsum[0] += __shfl_xor(lsum[0], 32, 64);
    lsum[1] += __shfl_xor(lsum[1], 32, 64);
    if (hi == 0) {
        ll[wave][r31]      = 1.0f / lsum[0];
        ll[wave][32 + r31] = 1.0f / lsum[1];
    }

    const int b = bh >> 4, h = bh & 15;
    #pragma unroll
    for (int g = 0; g < 2; ++g) {
        float sc[16];
        #pragma unroll
        for (int r = 0; r < 16; ++r)
            sc[r] = ll[wave][g * 32 + (r & 3) + 4 * hi + 8 * (r >> 2)];
        #pragma unroll
        for (int st = 0; st < 2; ++st)
            #pragma unroll
            for (int r = 0; r < 16; ++r) {
                const int q = (r & 3) + 4 * hi + 8 * (r >> 2);
                O[((size_t)(b * Tv + q0 + wave * 64 + g * 32 + q)) * Ev
                  + h * Sv + st * 32 + r31] = f2bf(oa[g][st][r] * sc[r]);
            }
    }
}

// ---------------------------------------------------------------------------
// Kernel 3: output projection — REVERTED to the m97 structure (async16
// global_load_lds, single buffer, 2 barriers, BK=32). Per m249/m230 the
// reg-staged form costs ~16% on the 2-phase GEMM shape; R8 changed this
// bundled with qkv so the sign was never isolated. This round isolates it.
// ---------------------------------------------------------------------------
__global__ __launch_bounds__(256) void proj_kernel(
    const ushort* __restrict__ A, const ushort* __restrict__ Bw,
    const float* __restrict__ bp, float* __restrict__ C)
{
    __shared__ ushort Asm[128 * 32];
    __shared__ ushort Bsm[128 * 32];
    const int tid  = threadIdx.x;
    const int wave = tid >> 6;
    const int lane = tid & 63;
    const int m    = lane & 15;
    const int quad = lane >> 4;
    const int wm   = wave >> 1;
    const int wn   = wave & 1;
    const int m0   = blockIdx.x * 128;
    const int n0   = blockIdx.y * 128;

    f32x4 acc[4][4];
    #pragma unroll
    for (int i = 0; i < 4; ++i)
        #pragma unroll
        for (int j = 0; j < 4; ++j)
            acc[i][j] = (f32x4){0.f, 0.f, 0.f, 0.f};

    for (int k0 = 0; k0 < Ev; k0 += 32) {
        __syncthreads();
        #pragma unroll
        for (int j = 0; j < 2; ++j) {
            int c   = j * 256 + tid;
            int row = c >> 2;
            int col = (c & 3) * 8;
            async16(&Asm[c * 8], &A [(size_t)(m0 + row) * Ev + k0 + col]);
            async16(&Bsm[c * 8], &Bw[(size_t)(n0 + row) * Ev + k0 + col]);
        }
        __syncthreads();

        bf16x8 af[4], bf[4];
        #pragma unroll
        for (int i = 0; i < 4; ++i)
            af[i] = *(const bf16x8*)&Asm[(wm * 64 + i * 16 + m) * 32 + quad * 8];
        #pragma unroll
        for (int j = 0; j < 4; ++j)
            bf[j] = *(const bf16x8*)&Bsm[(wn * 64 + j * 16 + m) * 32 + quad * 8];
        #pragma unroll
        for (int i = 0; i < 4; ++i)
            #pragma unroll
            for (int j = 0; j < 4; ++j)
                acc[i][j] = __builtin_amdgcn_mfma_f32_16x16x32_bf16(
                    af[i], bf[j], acc[i][j], 0, 0, 0);
    }

    float bbv[4];
    #pragma unroll
    for (int j = 0; j < 4; ++j)
        bbv[j] = bp[n0 + wn * 64 + j * 16 + m];

    #pragma unroll
    for (int i = 0; i < 4; ++i)
        #pragma unroll
        for (int j = 0; j < 4; ++j)
            #pragma unroll
            for (int r = 0; r < 4; ++r)
                C[(size_t)(m0 + wm * 64 + i * 16 + quad * 4 + r) * Ev
                  + n0 + wn * 64 + j * 16 + m] = acc[i][j][r] + bbv[j];
}

// ---------------------------------------------------------------------------
// ws layout (ushort units): Q 8.4M | K 8.4M | Vt 8.4M | O 8.4M | Wpb 1M
// ---------------------------------------------------------------------------
extern "C" void kernel_launch(void* const* d_in, const int* in_sizes, int n_in,
                              void* d_out, int out_size, void* d_ws, size_t ws_size,
                              hipStream_t stream) {
    const float* x  = (const float*)d_in[0];
    const float* Wk = (const float*)d_in[1];
    const float* Wq = (const float*)d_in[2];
    const float* Wv = (const float*)d_in[3];
    const float* Wp = (const float*)d_in[4];
    const float* bp = (const float*)d_in[5];
    float* out = (float*)d_out;

    ushort* Q   = (ushort*)d_ws;
    ushort* K   = Q   + 8388608;
    ushort* Vt  = K   + 8388608;
    ushort* O   = Vt  + 8388608;
    ushort* Wpb = O   + 8388608;

    qkv_kernel<<<2731, 192, 0, stream>>>(x, Wq, Wk, Wv, Wp, Wpb, Q, K, Vt);
    attn_kernel<<<512, 256, 0, stream>>>(Q, K, Vt, O);
    proj_kernel<<<dim3(64, 8), 256, 0, stream>>>(O, Wpb, bp, out);
}

// Round 11
// 207.394 us; speedup vs baseline: 1.0111x; 1.0020x over previous
//
#include <hip/hip_runtime.h>
#include <hip/hip_bf16.h>

#define Bv 4
#define Tv 2048
#define Ev 1024
#define Hv 16
#define Sv 64

typedef __attribute__((ext_vector_type(8))) short bf16x8;
typedef __attribute__((ext_vector_type(4))) float f32x4;
typedef __attribute__((ext_vector_type(16))) float f32x16;

__device__ __forceinline__ ushort f2bf(float f) {
    unsigned u = __float_as_uint(f);
    u = (u + 0x7FFFu + ((u >> 16) & 1u)) >> 16;
    return (ushort)u;
}
// RNE pack via v_cvt_pk_bf16_f32 (header lowers to HW instr on gfx950)
__device__ __forceinline__ unsigned pkrn(float a, float b) {
    __hip_bfloat162 t = __float22bfloat162_rn(make_float2(a, b));
    unsigned r; __builtin_memcpy(&r, &t, 4); return r;
}
// truncation pack, 1 VALU op (v_perm_b32): {lo=a_trunc, hi=b_trunc}
__device__ __forceinline__ unsigned pktr(float a, float b) {
    return __builtin_amdgcn_perm(__float_as_uint(b), __float_as_uint(a), 0x07060302u);
}

// async global->LDS, 16B per lane (global_load_lds_dwordx4)
__device__ __forceinline__ void async16(void* lds, const void* g) {
    __builtin_amdgcn_global_load_lds(
        (const __attribute__((address_space(1))) unsigned int*)g,
        (__attribute__((address_space(3))) unsigned int*)lds, 16, 0, 0);
}

// ---------------------------------------------------------------------------
// Kernel 1: QKV projection + Wp cast. R10 analysis: R8's "store swap" made
// Q/K stores WORSE (64 scalar 2B stores/lane vs 16 uint2 — 4x the store
// instruction count at the same line count); R8's win was the x-staging.
// This version: R8's LDS-staged xf + fused Wp cast, but Q/K branch reverted
// to the pre-R8 mfma(wf,xf) + uint2-store form (verified correct R0-R7).
// ---------------------------------------------------------------------------
__global__ __launch_bounds__(192) void qkv_kernel(
    const float* __restrict__ x,
    const float* __restrict__ Wq, const float* __restrict__ Wk,
    const float* __restrict__ Wv, const float* __restrict__ Wp,
    ushort* __restrict__ Wpb,
    ushort* __restrict__ Q, ushort* __restrict__ K, ushort* __restrict__ Vt)
{
    // ---- fused Wp cast blocks (683 x 192 x 8 floats >= 1M, guarded) ----
    if (blockIdx.x >= 2048) {
        size_t i = ((size_t)(blockIdx.x - 2048) * 192 + threadIdx.x) * 8;
        if (i < (size_t)Ev * Ev) {
            float4 v0 = *(const float4*)(Wp + i);
            float4 v1 = *(const float4*)(Wp + i + 4);
            uint4 o = {pkrn(v0.x, v0.y), pkrn(v0.z, v0.w),
                       pkrn(v1.x, v1.y), pkrn(v1.z, v1.w)};
            *(uint4*)(Wpb + i) = o;
        }
        return;
    }

    __shared__ float xs[16 * 256];   // [token][4 heads * 64], granule-swizzled

    const int tid  = threadIdx.x;
    const int wave = tid >> 6;        // 0=Q 1=K 2=V
    const int lane = tid & 63;
    const int m    = lane & 15;
    const int quad = lane >> 4;

    const int tt = blockIdx.x >> 2;   // 0..511 token tile
    const int hg = blockIdx.x & 3;    // head group
    const int g0 = tt * 16;
    const int b  = g0 >> 11;
    const int t0 = g0 & 2047;

    // stage x tile: chunk c (16B) -> xs linear; source granule pre-swizzled
    #pragma unroll
    for (int pass = 0; pass < 6; ++pass) {
        int c = pass * 192 + tid;
        if (c < 1024) {
            int tok  = c >> 6;
            int gsrc = (c & 63) ^ (tok & 7);
            async16(&xs[c * 4],
                    x + (size_t)(g0 + tok) * Ev + hg * 256 + gsrc * 4);
        }
    }

    // self-cast weight fragments (fp32 -> bf16, scale folded for Q)
    const float* Wsel = (wave == 0) ? Wq : ((wave == 1) ? Wk : Wv);
    const float wscale = (wave == 0) ? 0.03125f * 1.4426950408889634f : 1.0f;
    bf16x8 wf[4][2];
    #pragma unroll
    for (int ot = 0; ot < 4; ++ot)
        #pragma unroll
        for (int ks = 0; ks < 2; ++ks) {
            const float* ws = &Wsel[(ot * 16 + m) * 64 + ks * 32 + quad * 8];
            float4 w0 = *(const float4*)ws;
            float4 w1 = *(const float4*)(ws + 4);
            unsigned pk[4];
            pk[0] = pkrn(w0.x * wscale, w0.y * wscale);
            pk[1] = pkrn(w0.z * wscale, w0.w * wscale);
            pk[2] = pkrn(w1.x * wscale, w1.y * wscale);
            pk[3] = pkrn(w1.z * wscale, w1.w * wscale);
            wf[ot][ks] = *(bf16x8*)pk;
        }

    __syncthreads();   // x tile resident

    #pragma unroll
    for (int hi = 0; hi < 4; ++hi) {
        const int h  = hg * 4 + hi;
        const int bh = b * Hv + h;

        // xf from LDS: granule gc = hi*16 + ks*8 + quad*2, phys = gc^(m&7)
        bf16x8 xf[2];
        #pragma unroll
        for (int ks = 0; ks < 2; ++ks) {
            int gc = hi * 16 + ks * 8 + quad * 2;
            float4 v0 = *(const float4*)&xs[(m * 64 + ( gc      ^ (m & 7))) * 4];
            float4 v1 = *(const float4*)&xs[(m * 64 + ((gc + 1) ^ (m & 7))) * 4];
            unsigned pk[4];
            pk[0] = pkrn(v0.x, v0.y); pk[1] = pkrn(v0.z, v0.w);
            pk[2] = pkrn(v1.x, v1.y); pk[3] = pkrn(v1.z, v1.w);
            xf[ks] = *(bf16x8*)pk;
        }

        f32x4 acc[4];
        #pragma unroll
        for (int ot = 0; ot < 4; ++ot) acc[ot] = (f32x4){0.f, 0.f, 0.f, 0.f};

        if (wave < 2) {
            // pre-R8 form: D[o][t], uint2 stores (16/lane, 16-line txns)
            #pragma unroll
            for (int ks = 0; ks < 2; ++ks)
                #pragma unroll
                for (int ot = 0; ot < 4; ++ot)
                    acc[ot] = __builtin_amdgcn_mfma_f32_16x16x32_bf16(
                        wf[ot][ks], xf[ks], acc[ot], 0, 0, 0);
            ushort* dst = ((wave == 0) ? Q : K)
                        + ((size_t)bh * Tv + t0 + m) * Sv + quad * 4;
            #pragma unroll
            for (int ot = 0; ot < 4; ++ot) {
                uint2 w = {pkrn(acc[ot][0], acc[ot][1]), pkrn(acc[ot][2], acc[ot][3])};
                *(uint2*)(dst + ot * 16) = w;
            }
        } else {
            #pragma unroll
            for (int ks = 0; ks < 2; ++ks)
                #pragma unroll
                for (int st = 0; st < 4; ++st)
                    acc[st] = __builtin_amdgcn_mfma_f32_16x16x32_bf16(
                        xf[ks], wf[st][ks], acc[st], 0, 0, 0);
            ushort* vr = Vt + ((size_t)bh * Sv + m) * Tv + t0 + quad * 4;
            #pragma unroll
            for (int st = 0; st < 4; ++st) {
                uint2 w = {pkrn(acc[st][0], acc[st][1]), pkrn(acc[st][2], acc[st][3])};
                *(uint2*)(vr + (size_t)st * 16 * Tv) = w;
            }
        }
    }
}

// ---------------------------------------------------------------------------
// Kernel 2: flash attention v13 (R8/R10 verbatim — measured best ~76us).
// ---------------------------------------------------------------------------
__global__ __launch_bounds__(256, 2) void attn_kernel(
    const ushort* __restrict__ Q, const ushort* __restrict__ K,
    const ushort* __restrict__ Vt, ushort* __restrict__ O)
{
    __shared__ ushort kl[2][64 * 64];     // K tile  [key][d]   (swizzled)
    __shared__ ushort vl[2][64 * 64];     // Vt tile [s][key]   (swizzled)
    __shared__ float  ll[4][64];          // per-wave 1/lsum bounce

    const int tid  = threadIdx.x;
    const int wave = tid >> 6;
    const int lane = tid & 63;
    const int r31  = lane & 31;
    const int hi   = lane >> 5;
    const int bh   = blockIdx.x & 63;
    const int q0   = (blockIdx.x >> 6) << 8;   // query tile base (256)

    // Q B-frags: group g covers queries q0 + wave*64 + g*32 + r31,
    // k = ks*16 + hi*8 + j
    const ushort* Qb = Q + ((size_t)bh * Tv + q0 + wave * 64 + r31) * Sv + hi * 8;
    bf16x8 qf[2][4];
    #pragma unroll
    for (int g = 0; g < 2; ++g)
        #pragma unroll
        for (int ks = 0; ks < 4; ++ks)
            qf[g][ks] = *(const bf16x8*)(Qb + (size_t)g * 32 * Sv + ks * 16);

    f32x16 oa[2][2];
    #pragma unroll
    for (int g = 0; g < 2; ++g)
        #pragma unroll
        for (int st = 0; st < 2; ++st)
            #pragma unroll
            for (int r = 0; r < 16; ++r)
                oa[g][st][r] = 0.f;
    float lsum[2] = {0.f, 0.f};

    const ushort* Kb = K  + (size_t)bh * Tv * Sv;
    const ushort* Vb = Vt + (size_t)bh * Sv * Tv;

    // staging geometry (swizzled): chunk c -> row=c>>3, phys cg=c&7,
    // source col-group = (c&7) ^ (row&7)
    const int r0 = tid >> 3,         cg0 = (tid & 7) ^ (r0 & 7);
    const int r1 = (256 + tid) >> 3, cg1 = ((256 + tid) & 7) ^ (r1 & 7);
    const size_t koff0 = (size_t)r0 * Sv + cg0 * 8;
    const size_t koff1 = (size_t)r1 * Sv + cg1 * 8;
    const size_t voff0 = (size_t)r0 * Tv + cg0 * 8;
    const size_t voff1 = (size_t)r1 * Tv + cg1 * 8;
    const int swz = r31 & 7;

    // softmax + PV for one 32-query group (everything statically indexed)
    auto softpv = [&](const f32x16& sv, float& ls, f32x16* oag, int kp,
                      const bf16x8* vf) {
        float p[8];
        #pragma unroll
        for (int j = 0; j < 8; ++j)
            p[j] = __builtin_amdgcn_exp2f(sv[kp * 8 + j]);
        ls += ((p[0] + p[1]) + (p[2] + p[3]))
            + ((p[4] + p[5]) + (p[6] + p[7]));
        unsigned d0 = pktr(p[0], p[1]);
        unsigned d1 = pktr(p[2], p[3]);
        unsigned d2 = pktr(p[4], p[5]);
        unsigned d3 = pktr(p[6], p[7]);
        asm volatile("v_permlane32_swap_b32 %0, %1" : "+v"(d0), "+v"(d2));
        asm volatile("v_permlane32_swap_b32 %0, %1" : "+v"(d1), "+v"(d3));
        unsigned pw[4] = {d0, d1, d2, d3};
        bf16x8 pf = *(bf16x8*)pw;
        #pragma unroll
        for (int st = 0; st < 2; ++st)
            oag[st] = __builtin_amdgcn_mfma_f32_32x32x16_bf16(
                pf, vf[st], oag[st], 0, 0, 0);
    };

    // prologue: tile 0 -> buf0 (via regs), tile 1 -> regs
    uint4 rk0 = *(const uint4*)(Kb + koff0);
    uint4 rk1 = *(const uint4*)(Kb + koff1);
    uint4 rv0 = *(const uint4*)(Vb + voff0);
    uint4 rv1 = *(const uint4*)(Vb + voff1);
    *(uint4*)&kl[0][(size_t)tid * 8]         = rk0;
    *(uint4*)&kl[0][((size_t)tid + 256) * 8] = rk1;
    *(uint4*)&vl[0][(size_t)tid * 8]         = rv0;
    *(uint4*)&vl[0][((size_t)tid + 256) * 8] = rv1;
    rk0 = *(const uint4*)(Kb + (size_t)64 * Sv + koff0);
    rk1 = *(const uint4*)(Kb + (size_t)64 * Sv + koff1);
    rv0 = *(const uint4*)(Vb + 64 + voff0);
    rv1 = *(const uint4*)(Vb + 64 + voff1);
    __syncthreads();

    for (int k0 = 0; k0 < Tv; k0 += 64) {
        const int cur = (k0 >> 6) & 1;

        // stage tile t+1 from regs into the other buffer
        *(uint4*)&kl[cur ^ 1][(size_t)tid * 8]         = rk0;
        *(uint4*)&kl[cur ^ 1][((size_t)tid + 256) * 8] = rk1;
        *(uint4*)&vl[cur ^ 1][(size_t)tid * 8]         = rv0;
        *(uint4*)&vl[cur ^ 1][((size_t)tid + 256) * 8] = rv1;

        // issue tile t+2 loads; they land during the compute below
        int kn = k0 + 128; if (kn >= Tv) kn = 0;   // clamped dummy on tail
        rk0 = *(const uint4*)(Kb + (size_t)kn * Sv + koff0);
        rk1 = *(const uint4*)(Kb + (size_t)kn * Sv + koff1);
        rv0 = *(const uint4*)(Vb + kn + voff0);
        rv1 = *(const uint4*)(Vb + kn + voff1);

        #pragma unroll
        for (int kt = 0; kt < 2; ++kt) {
            // kf loaded ONCE, reused for both query groups
            bf16x8 kf[4];
            #pragma unroll
            for (int ks = 0; ks < 4; ++ks)
                kf[ks] = *(const bf16x8*)
                    &kl[cur][(kt * 32 + r31) * 64 + (((ks * 2 + hi) ^ swz) * 8)];

            // S^T = K·Q^T (32x32x16): D col = q = r31,
            // row = key_local = (r&3) + 4*hi + 8*(r>>2)
            f32x16 s0, s1;
            #pragma unroll
            for (int r = 0; r < 16; ++r) { s0[r] = 0.f; s1[r] = 0.f; }
            #pragma unroll
            for (int ks = 0; ks < 4; ++ks)
                s0 = __builtin_amdgcn_mfma_f32_32x32x16_bf16(
                    kf[ks], qf[0][ks], s0, 0, 0, 0);
            #pragma unroll
            for (int ks = 0; ks < 4; ++ks)
                s1 = __builtin_amdgcn_mfma_f32_32x32x16_bf16(
                    kf[ks], qf[1][ks], s1, 0, 0, 0);

            #pragma unroll
            for (int kp = 0; kp < 2; ++kp) {
                const int kc = (kt * 2 + kp) * 2 + hi;  // V col chunk
                bf16x8 vf[2];
                #pragma unroll
                for (int st = 0; st < 2; ++st)
                    vf[st] = *(const bf16x8*)
                        &vl[cur][(st * 32 + r31) * 64 + ((kc ^ swz) * 8)];
                softpv(s0, lsum[0], oa[0], kp, vf);
                softpv(s1, lsum[1], oa[1], kp, vf);
            }
        }

        // ONE barrier per iter: publishes this iter's ds_writes (lgkmcnt),
        // closes the read window on buf[cur], drains the t+2 loads (which
        // just had the whole compute phase to land).
        __syncthreads();
    }

    // row sum: halves hold disjoint key sets for the same q -> one xor-32
    lsum[0] += __shfl_xor(lsum[0], 32, 64);
    lsum[1] += __shfl_xor(lsum[1], 32, 64);
    if (hi == 0) {
        ll[wave][r31]      = 1.0f / lsum[0];
        ll[wave][32 + r31] = 1.0f / lsum[1];
    }

    const int b = bh >> 4, h = bh & 15;
    #pragma unroll
    for (int g = 0; g < 2; ++g) {
        float sc[16];
        #pragma unroll
        for (int r = 0; r < 16; ++r)
            sc[r] = ll[wave][g * 32 + (r & 3) + 4 * hi + 8 * (r >> 2)];
        #pragma unroll
        for (int st = 0; st < 2; ++st)
            #pragma unroll
            for (int r = 0; r < 16; ++r) {
                const int q = (r & 3) + 4 * hi + 8 * (r >> 2);
                O[((size_t)(b * Tv + q0 + wave * 64 + g * 32 + q)) * Ev
                  + h * Sv + st * 32 + r31] = f2bf(oa[g][st][r] * sc[r]);
            }
    }
}

// ---------------------------------------------------------------------------
// Kernel 3: output projection — OCCUPANCY FIX. Old grid 512 blocks = exactly
// 2 blocks/CU = 2 waves/SIMD (grid-limited; m102 shows this regime at
// 90-300 TF). New: BM=128 x BN=64 tiles -> grid 64x16 = 1024 blocks =
// 4 blocks/CU = 4 waves/SIMD, double the latency-hiding TLP. LDS 12KB.
// Same m97-style async16 staging + 2-barrier loop, BK=32.
// ---------------------------------------------------------------------------
__global__ __launch_bounds__(256) void proj_kernel(
    const ushort* __restrict__ A, const ushort* __restrict__ Bw,
    const float* __restrict__ bp, float* __restrict__ C)
{
    __shared__ ushort Asm[128 * 32];
    __shared__ ushort Bsm[64 * 32];
    const int tid  = threadIdx.x;
    const int wave = tid >> 6;
    const int lane = tid & 63;
    const int m    = lane & 15;
    const int quad = lane >> 4;
    const int wm   = wave >> 1;          // 0..1: M half (64 rows)
    const int wn   = wave & 1;           // 0..1: N half (32 cols)
    const int m0   = blockIdx.x * 128;
    const int n0   = blockIdx.y * 64;

    f32x4 acc[4][2];
    #pragma unroll
    for (int i = 0; i < 4; ++i)
        #pragma unroll
        for (int j = 0; j < 2; ++j)
            acc[i][j] = (f32x4){0.f, 0.f, 0.f, 0.f};

    for (int k0 = 0; k0 < Ev; k0 += 32) {
        __syncthreads();
        // A tile: 128x32 = 512 chunks (2/thread); B tile: 64x32 = 256 (1/thread)
        #pragma unroll
        for (int j = 0; j < 2; ++j) {
            int c   = j * 256 + tid;
            int row = c >> 2;
            int col = (c & 3) * 8;
            async16(&Asm[c * 8], &A[(size_t)(m0 + row) * Ev + k0 + col]);
        }
        {
            int row = tid >> 2;
            int col = (tid & 3) * 8;
            async16(&Bsm[tid * 8], &Bw[(size_t)(n0 + row) * Ev + k0 + col]);
        }
        __syncthreads();

        bf16x8 af[4], bf[2];
        #pragma unroll
        for (int i = 0; i < 4; ++i)
            af[i] = *(const bf16x8*)&Asm[(wm * 64 + i * 16 + m) * 32 + quad * 8];
        #pragma unroll
        for (int j = 0; j < 2; ++j)
            bf[j] = *(const bf16x8*)&Bsm[(wn * 32 + j * 16 + m) * 32 + quad * 8];
        #pragma unroll
        for (int i = 0; i < 4; ++i)
            #pragma unroll
            for (int j = 0; j < 2; ++j)
                acc[i][j] = __builtin_amdgcn_mfma_f32_16x16x32_bf16(
                    af[i], bf[j], acc[i][j], 0, 0, 0);
    }

    float bbv[2];
    #pragma unroll
    for (int j = 0; j < 2; ++j)
        bbv[j] = bp[n0 + wn * 32 + j * 16 + m];

    #pragma unroll
    for (int i = 0; i < 4; ++i)
        #pragma unroll
        for (int j = 0; j < 2; ++j)
            #pragma unroll
            for (int r = 0; r < 4; ++r)
                C[(size_t)(m0 + wm * 64 + i * 16 + quad * 4 + r) * Ev
                  + n0 + wn * 32 + j * 16 + m] = acc[i][j][r] + bbv[j];
}

// ---------------------------------------------------------------------------
// ws layout (ushort units): Q 8.4M | K 8.4M | Vt 8.4M | O 8.4M | Wpb 1M
// ---------------------------------------------------------------------------
extern "C" void kernel_launch(void* const* d_in, const int* in_sizes, int n_in,
                              void* d_out, int out_size, void* d_ws, size_t ws_size,
                              hipStream_t stream) {
    const float* x  = (const float*)d_in[0];
    const float* Wk = (const float*)d_in[1];
    const float* Wq = (const float*)d_in[2];
    const float* Wv = (const float*)d_in[3];
    const float* Wp = (const float*)d_in[4];
    const float* bp = (const float*)d_in[5];
    float* out = (float*)d_out;

    ushort* Q   = (ushort*)d_ws;
    ushort* K   = Q   + 8388608;
    ushort* Vt  = K   + 8388608;
    ushort* O   = Vt  + 8388608;
    ushort* Wpb = O   + 8388608;

    qkv_kernel<<<2731, 192, 0, stream>>>(x, Wq, Wk, Wv, Wp, Wpb, Q, K, Vt);
    attn_kernel<<<512, 256, 0, stream>>>(Q, K, Vt, O);
    proj_kernel<<<dim3(64, 16), 256, 0, stream>>>(O, Wpb, bp, out);
}

// Round 12
// 203.510 us; speedup vs baseline: 1.0304x; 1.0191x over previous
//
#include <hip/hip_runtime.h>
#include <hip/hip_bf16.h>

#define Bv 4
#define Tv 2048
#define Ev 1024
#define Hv 16
#define Sv 64

typedef __attribute__((ext_vector_type(8))) short bf16x8;
typedef __attribute__((ext_vector_type(4))) float f32x4;
typedef __attribute__((ext_vector_type(16))) float f32x16;

__device__ __forceinline__ ushort f2bf(float f) {
    unsigned u = __float_as_uint(f);
    u = (u + 0x7FFFu + ((u >> 16) & 1u)) >> 16;
    return (ushort)u;
}
// RNE pack via v_cvt_pk_bf16_f32 (header lowers to HW instr on gfx950)
__device__ __forceinline__ unsigned pkrn(float a, float b) {
    __hip_bfloat162 t = __float22bfloat162_rn(make_float2(a, b));
    unsigned r; __builtin_memcpy(&r, &t, 4); return r;
}
// truncation pack, 1 VALU op (v_perm_b32): {lo=a_trunc, hi=b_trunc}
__device__ __forceinline__ unsigned pktr(float a, float b) {
    return __builtin_amdgcn_perm(__float_as_uint(b), __float_as_uint(a), 0x07060302u);
}

// async global->LDS, 16B per lane (global_load_lds_dwordx4)
__device__ __forceinline__ void async16(void* lds, const void* g) {
    __builtin_amdgcn_global_load_lds(
        (const __attribute__((address_space(1))) unsigned int*)g,
        (__attribute__((address_space(3))) unsigned int*)lds, 16, 0, 0);
}

// ---------------------------------------------------------------------------
// Kernel 1: QKV projection + Wp cast (R11 verbatim: LDS-staged x, fused Wp
// cast, uint2 Q/K stores).
// ---------------------------------------------------------------------------
__global__ __launch_bounds__(192) void qkv_kernel(
    const float* __restrict__ x,
    const float* __restrict__ Wq, const float* __restrict__ Wk,
    const float* __restrict__ Wv, const float* __restrict__ Wp,
    ushort* __restrict__ Wpb,
    ushort* __restrict__ Q, ushort* __restrict__ K, ushort* __restrict__ Vt)
{
    // ---- fused Wp cast blocks (683 x 192 x 8 floats >= 1M, guarded) ----
    if (blockIdx.x >= 2048) {
        size_t i = ((size_t)(blockIdx.x - 2048) * 192 + threadIdx.x) * 8;
        if (i < (size_t)Ev * Ev) {
            float4 v0 = *(const float4*)(Wp + i);
            float4 v1 = *(const float4*)(Wp + i + 4);
            uint4 o = {pkrn(v0.x, v0.y), pkrn(v0.z, v0.w),
                       pkrn(v1.x, v1.y), pkrn(v1.z, v1.w)};
            *(uint4*)(Wpb + i) = o;
        }
        return;
    }

    __shared__ float xs[16 * 256];   // [token][4 heads * 64], granule-swizzled

    const int tid  = threadIdx.x;
    const int wave = tid >> 6;        // 0=Q 1=K 2=V
    const int lane = tid & 63;
    const int m    = lane & 15;
    const int quad = lane >> 4;

    const int tt = blockIdx.x >> 2;   // 0..511 token tile
    const int hg = blockIdx.x & 3;    // head group
    const int g0 = tt * 16;
    const int b  = g0 >> 11;
    const int t0 = g0 & 2047;

    // stage x tile: chunk c (16B) -> xs linear; source granule pre-swizzled
    #pragma unroll
    for (int pass = 0; pass < 6; ++pass) {
        int c = pass * 192 + tid;
        if (c < 1024) {
            int tok  = c >> 6;
            int gsrc = (c & 63) ^ (tok & 7);
            async16(&xs[c * 4],
                    x + (size_t)(g0 + tok) * Ev + hg * 256 + gsrc * 4);
        }
    }

    // self-cast weight fragments (fp32 -> bf16, scale folded for Q)
    const float* Wsel = (wave == 0) ? Wq : ((wave == 1) ? Wk : Wv);
    const float wscale = (wave == 0) ? 0.03125f * 1.4426950408889634f : 1.0f;
    bf16x8 wf[4][2];
    #pragma unroll
    for (int ot = 0; ot < 4; ++ot)
        #pragma unroll
        for (int ks = 0; ks < 2; ++ks) {
            const float* ws = &Wsel[(ot * 16 + m) * 64 + ks * 32 + quad * 8];
            float4 w0 = *(const float4*)ws;
            float4 w1 = *(const float4*)(ws + 4);
            unsigned pk[4];
            pk[0] = pkrn(w0.x * wscale, w0.y * wscale);
            pk[1] = pkrn(w0.z * wscale, w0.w * wscale);
            pk[2] = pkrn(w1.x * wscale, w1.y * wscale);
            pk[3] = pkrn(w1.z * wscale, w1.w * wscale);
            wf[ot][ks] = *(bf16x8*)pk;
        }

    __syncthreads();   // x tile resident

    #pragma unroll
    for (int hi = 0; hi < 4; ++hi) {
        const int h  = hg * 4 + hi;
        const int bh = b * Hv + h;

        // xf from LDS: granule gc = hi*16 + ks*8 + quad*2, phys = gc^(m&7)
        bf16x8 xf[2];
        #pragma unroll
        for (int ks = 0; ks < 2; ++ks) {
            int gc = hi * 16 + ks * 8 + quad * 2;
            float4 v0 = *(const float4*)&xs[(m * 64 + ( gc      ^ (m & 7))) * 4];
            float4 v1 = *(const float4*)&xs[(m * 64 + ((gc + 1) ^ (m & 7))) * 4];
            unsigned pk[4];
            pk[0] = pkrn(v0.x, v0.y); pk[1] = pkrn(v0.z, v0.w);
            pk[2] = pkrn(v1.x, v1.y); pk[3] = pkrn(v1.z, v1.w);
            xf[ks] = *(bf16x8*)pk;
        }

        f32x4 acc[4];
        #pragma unroll
        for (int ot = 0; ot < 4; ++ot) acc[ot] = (f32x4){0.f, 0.f, 0.f, 0.f};

        if (wave < 2) {
            #pragma unroll
            for (int ks = 0; ks < 2; ++ks)
                #pragma unroll
                for (int ot = 0; ot < 4; ++ot)
                    acc[ot] = __builtin_amdgcn_mfma_f32_16x16x32_bf16(
                        wf[ot][ks], xf[ks], acc[ot], 0, 0, 0);
            ushort* dst = ((wave == 0) ? Q : K)
                        + ((size_t)bh * Tv + t0 + m) * Sv + quad * 4;
            #pragma unroll
            for (int ot = 0; ot < 4; ++ot) {
                uint2 w = {pkrn(acc[ot][0], acc[ot][1]), pkrn(acc[ot][2], acc[ot][3])};
                *(uint2*)(dst + ot * 16) = w;
            }
        } else {
            #pragma unroll
            for (int ks = 0; ks < 2; ++ks)
                #pragma unroll
                for (int st = 0; st < 4; ++st)
                    acc[st] = __builtin_amdgcn_mfma_f32_16x16x32_bf16(
                        xf[ks], wf[st][ks], acc[st], 0, 0, 0);
            ushort* vr = Vt + ((size_t)bh * Sv + m) * Tv + t0 + quad * 4;
            #pragma unroll
            for (int st = 0; st < 4; ++st) {
                uint2 w = {pkrn(acc[st][0], acc[st][1]), pkrn(acc[st][2], acc[st][3])};
                *(uint2*)(vr + (size_t)st * 16 * Tv) = w;
            }
        }
    }
}

// ---------------------------------------------------------------------------
// Kernel 2: flash attention v16 — v13 + QK HOIST. v13's kt=1 QK sat after
// kt=0's whole softmax chain; at 2 waves/SIMD each MFMA was effectively
// ~17cy (MfmaUtil 38% vs 18% throughput-theoretical = latency exposure).
// Now all 4 QK chains (2 groups x 2 kt, independent accumulators, 4-way
// ILP, 16 MFMAs) run as one block at iter top — overlapping the staging
// ds_writes — then the 8 softpv steps follow with PV at 1-step skew from
// softmax. Same math, same accumulation order (lsum/oa identical).
// VGPR ~210 (4 live f32x16 sacc) — still 2 waves/SIMD.
// ---------------------------------------------------------------------------
__global__ __launch_bounds__(256, 2) void attn_kernel(
    const ushort* __restrict__ Q, const ushort* __restrict__ K,
    const ushort* __restrict__ Vt, ushort* __restrict__ O)
{
    __shared__ ushort kl[2][64 * 64];     // K tile  [key][d]   (swizzled)
    __shared__ ushort vl[2][64 * 64];     // Vt tile [s][key]   (swizzled)
    __shared__ float  ll[4][64];          // per-wave 1/lsum bounce

    const int tid  = threadIdx.x;
    const int wave = tid >> 6;
    const int lane = tid & 63;
    const int r31  = lane & 31;
    const int hi   = lane >> 5;
    const int bh   = blockIdx.x & 63;
    const int q0   = (blockIdx.x >> 6) << 8;   // query tile base (256)

    // Q B-frags: group g covers queries q0 + wave*64 + g*32 + r31,
    // k = ks*16 + hi*8 + j
    const ushort* Qb = Q + ((size_t)bh * Tv + q0 + wave * 64 + r31) * Sv + hi * 8;
    bf16x8 qf[2][4];
    #pragma unroll
    for (int g = 0; g < 2; ++g)
        #pragma unroll
        for (int ks = 0; ks < 4; ++ks)
            qf[g][ks] = *(const bf16x8*)(Qb + (size_t)g * 32 * Sv + ks * 16);

    f32x16 oa[2][2];
    #pragma unroll
    for (int g = 0; g < 2; ++g)
        #pragma unroll
        for (int st = 0; st < 2; ++st)
            #pragma unroll
            for (int r = 0; r < 16; ++r)
                oa[g][st][r] = 0.f;
    float lsum[2] = {0.f, 0.f};

    const ushort* Kb = K  + (size_t)bh * Tv * Sv;
    const ushort* Vb = Vt + (size_t)bh * Sv * Tv;

    // staging geometry (swizzled): chunk c -> row=c>>3, phys cg=c&7,
    // source col-group = (c&7) ^ (row&7)
    const int r0 = tid >> 3,         cg0 = (tid & 7) ^ (r0 & 7);
    const int r1 = (256 + tid) >> 3, cg1 = ((256 + tid) & 7) ^ (r1 & 7);
    const size_t koff0 = (size_t)r0 * Sv + cg0 * 8;
    const size_t koff1 = (size_t)r1 * Sv + cg1 * 8;
    const size_t voff0 = (size_t)r0 * Tv + cg0 * 8;
    const size_t voff1 = (size_t)r1 * Tv + cg1 * 8;
    const int swz = r31 & 7;

    // softmax + PV for one 32-query group (everything statically indexed)
    auto softpv = [&](const f32x16& sv, float& ls, f32x16* oag, int kp,
                      const bf16x8* vf) {
        float p[8];
        #pragma unroll
        for (int j = 0; j < 8; ++j)
            p[j] = __builtin_amdgcn_exp2f(sv[kp * 8 + j]);
        ls += ((p[0] + p[1]) + (p[2] + p[3]))
            + ((p[4] + p[5]) + (p[6] + p[7]));
        unsigned d0 = pktr(p[0], p[1]);
        unsigned d1 = pktr(p[2], p[3]);
        unsigned d2 = pktr(p[4], p[5]);
        unsigned d3 = pktr(p[6], p[7]);
        asm volatile("v_permlane32_swap_b32 %0, %1" : "+v"(d0), "+v"(d2));
        asm volatile("v_permlane32_swap_b32 %0, %1" : "+v"(d1), "+v"(d3));
        unsigned pw[4] = {d0, d1, d2, d3};
        bf16x8 pf = *(bf16x8*)pw;
        #pragma unroll
        for (int st = 0; st < 2; ++st)
            oag[st] = __builtin_amdgcn_mfma_f32_32x32x16_bf16(
                pf, vf[st], oag[st], 0, 0, 0);
    };

    // prologue: tile 0 -> buf0 (via regs), tile 1 -> regs
    uint4 rk0 = *(const uint4*)(Kb + koff0);
    uint4 rk1 = *(const uint4*)(Kb + koff1);
    uint4 rv0 = *(const uint4*)(Vb + voff0);
    uint4 rv1 = *(const uint4*)(Vb + voff1);
    *(uint4*)&kl[0][(size_t)tid * 8]         = rk0;
    *(uint4*)&kl[0][((size_t)tid + 256) * 8] = rk1;
    *(uint4*)&vl[0][(size_t)tid * 8]         = rv0;
    *(uint4*)&vl[0][((size_t)tid + 256) * 8] = rv1;
    rk0 = *(const uint4*)(Kb + (size_t)64 * Sv + koff0);
    rk1 = *(const uint4*)(Kb + (size_t)64 * Sv + koff1);
    rv0 = *(const uint4*)(Vb + 64 + voff0);
    rv1 = *(const uint4*)(Vb + 64 + voff1);
    __syncthreads();

    for (int k0 = 0; k0 < Tv; k0 += 64) {
        const int cur = (k0 >> 6) & 1;

        // stage tile t+1 from regs into the other buffer
        *(uint4*)&kl[cur ^ 1][(size_t)tid * 8]         = rk0;
        *(uint4*)&kl[cur ^ 1][((size_t)tid + 256) * 8] = rk1;
        *(uint4*)&vl[cur ^ 1][(size_t)tid * 8]         = rv0;
        *(uint4*)&vl[cur ^ 1][((size_t)tid + 256) * 8] = rv1;

        // issue tile t+2 loads; they land during the compute below
        int kn = k0 + 128; if (kn >= Tv) kn = 0;   // clamped dummy on tail
        rk0 = *(const uint4*)(Kb + (size_t)kn * Sv + koff0);
        rk1 = *(const uint4*)(Kb + (size_t)kn * Sv + koff1);
        rv0 = *(const uint4*)(Vb + kn + voff0);
        rv1 = *(const uint4*)(Vb + kn + voff1);

        // ---- hoisted QK: all kf reads, then 4 independent MFMA chains ----
        bf16x8 kf0[4], kf1[4];
        #pragma unroll
        for (int ks = 0; ks < 4; ++ks)
            kf0[ks] = *(const bf16x8*)
                &kl[cur][(r31) * 64 + (((ks * 2 + hi) ^ swz) * 8)];
        #pragma unroll
        for (int ks = 0; ks < 4; ++ks)
            kf1[ks] = *(const bf16x8*)
                &kl[cur][(32 + r31) * 64 + (((ks * 2 + hi) ^ swz) * 8)];

        f32x16 s0a, s1a, s0b, s1b;
        #pragma unroll
        for (int r = 0; r < 16; ++r) {
            s0a[r] = 0.f; s1a[r] = 0.f; s0b[r] = 0.f; s1b[r] = 0.f;
        }
        #pragma unroll
        for (int ks = 0; ks < 4; ++ks) {
            s0a = __builtin_amdgcn_mfma_f32_32x32x16_bf16(kf0[ks], qf[0][ks], s0a, 0, 0, 0);
            s1a = __builtin_amdgcn_mfma_f32_32x32x16_bf16(kf0[ks], qf[1][ks], s1a, 0, 0, 0);
            s0b = __builtin_amdgcn_mfma_f32_32x32x16_bf16(kf1[ks], qf[0][ks], s0b, 0, 0, 0);
            s1b = __builtin_amdgcn_mfma_f32_32x32x16_bf16(kf1[ks], qf[1][ks], s1b, 0, 0, 0);
        }

        // ---- softmax + PV (kt=0 uses s*a, kt=1 uses s*b; order as v13) ----
        #pragma unroll
        for (int kp = 0; kp < 2; ++kp) {
            const int kc = kp * 2 + hi;             // kt=0 V col chunk
            bf16x8 vf[2];
            #pragma unroll
            for (int st = 0; st < 2; ++st)
                vf[st] = *(const bf16x8*)
                    &vl[cur][(st * 32 + r31) * 64 + ((kc ^ swz) * 8)];
            softpv(s0a, lsum[0], oa[0], kp, vf);
            softpv(s1a, lsum[1], oa[1], kp, vf);
        }
        #pragma unroll
        for (int kp = 0; kp < 2; ++kp) {
            const int kc = (2 + kp) * 2 + hi;       // kt=1 V col chunk
            bf16x8 vf[2];
            #pragma unroll
            for (int st = 0; st < 2; ++st)
                vf[st] = *(const bf16x8*)
                    &vl[cur][(st * 32 + r31) * 64 + ((kc ^ swz) * 8)];
            softpv(s0b, lsum[0], oa[0], kp, vf);
            softpv(s1b, lsum[1], oa[1], kp, vf);
        }

        // ONE barrier per iter: publishes this iter's ds_writes (lgkmcnt),
        // closes the read window on buf[cur], drains the t+2 loads.
        __syncthreads();
    }

    // row sum: halves hold disjoint key sets for the same q -> one xor-32
    lsum[0] += __shfl_xor(lsum[0], 32, 64);
    lsum[1] += __shfl_xor(lsum[1], 32, 64);
    if (hi == 0) {
        ll[wave][r31]      = 1.0f / lsum[0];
        ll[wave][32 + r31] = 1.0f / lsum[1];
    }

    const int b = bh >> 4, h = bh & 15;
    #pragma unroll
    for (int g = 0; g < 2; ++g) {
        float sc[16];
        #pragma unroll
        for (int r = 0; r < 16; ++r)
            sc[r] = ll[wave][g * 32 + (r & 3) + 4 * hi + 8 * (r >> 2)];
        #pragma unroll
        for (int st = 0; st < 2; ++st)
            #pragma unroll
            for (int r = 0; r < 16; ++r) {
                const int q = (r & 3) + 4 * hi + 8 * (r >> 2);
                O[((size_t)(b * Tv + q0 + wave * 64 + g * 32 + q)) * Ev
                  + h * Sv + st * 32 + r31] = f2bf(oa[g][st][r] * sc[r]);
            }
    }
}

// ---------------------------------------------------------------------------
// Kernel 3: output projection — R8's reg-staged double-buffer (the form in
// the best-total round, 205.8). BM=BN=128, ONE barrier per K-step.
// ---------------------------------------------------------------------------
__global__ __launch_bounds__(256) void proj_kernel(
    const ushort* __restrict__ A, const ushort* __restrict__ Bw,
    const float* __restrict__ bp, float* __restrict__ C)
{
    __shared__ ushort Asm[2][128 * 32];
    __shared__ ushort Bsm[2][128 * 32];
    const int tid  = threadIdx.x;
    const int wave = tid >> 6;
    const int lane = tid & 63;
    const int m    = lane & 15;
    const int quad = lane >> 4;
    const int wm   = wave >> 1;
    const int wn   = wave & 1;
    const int m0   = blockIdx.x * 128;
    const int n0   = blockIdx.y * 128;

    f32x4 acc[4][4];
    #pragma unroll
    for (int i = 0; i < 4; ++i)
        #pragma unroll
        for (int j = 0; j < 4; ++j)
            acc[i][j] = (f32x4){0.f, 0.f, 0.f, 0.f};

    const int row0 = tid >> 2,         col0 = (tid & 3) * 8;
    const int row1 = (256 + tid) >> 2, col1 = ((256 + tid) & 3) * 8;

    // prologue: k=0 -> buf0 (via regs); k=32 -> regs
    uint4 a0 = *(const uint4*)&A [(size_t)(m0 + row0) * Ev + col0];
    uint4 a1 = *(const uint4*)&A [(size_t)(m0 + row1) * Ev + col1];
    uint4 b0 = *(const uint4*)&Bw[(size_t)(n0 + row0) * Ev + col0];
    uint4 b1 = *(const uint4*)&Bw[(size_t)(n0 + row1) * Ev + col1];
    *(uint4*)&Asm[0][(size_t)tid * 8]         = a0;
    *(uint4*)&Asm[0][((size_t)tid + 256) * 8] = a1;
    *(uint4*)&Bsm[0][(size_t)tid * 8]         = b0;
    *(uint4*)&Bsm[0][((size_t)tid + 256) * 8] = b1;
    a0 = *(const uint4*)&A [(size_t)(m0 + row0) * Ev + 32 + col0];
    a1 = *(const uint4*)&A [(size_t)(m0 + row1) * Ev + 32 + col1];
    b0 = *(const uint4*)&Bw[(size_t)(n0 + row0) * Ev + 32 + col0];
    b1 = *(const uint4*)&Bw[(size_t)(n0 + row1) * Ev + 32 + col1];
    __syncthreads();

    for (int it = 0; it < 32; ++it) {
        const int cur = it & 1;
        if (it < 31) {
            // stage k-step it+1 from regs into the other buffer
            *(uint4*)&Asm[cur ^ 1][(size_t)tid * 8]         = a0;
            *(uint4*)&Asm[cur ^ 1][((size_t)tid + 256) * 8] = a1;
            *(uint4*)&Bsm[cur ^ 1][(size_t)tid * 8]         = b0;
            *(uint4*)&Bsm[cur ^ 1][((size_t)tid + 256) * 8] = b1;
            // issue k-step it+2 loads; land during the MFMAs below
            int kn = (it + 2) * 32; if (kn >= Ev) kn = 0;  // clamped tail
            a0 = *(const uint4*)&A [(size_t)(m0 + row0) * Ev + kn + col0];
            a1 = *(const uint4*)&A [(size_t)(m0 + row1) * Ev + kn + col1];
            b0 = *(const uint4*)&Bw[(size_t)(n0 + row0) * Ev + kn + col0];
            b1 = *(const uint4*)&Bw[(size_t)(n0 + row1) * Ev + kn + col1];
        }

        bf16x8 af[4], bf[4];
        #pragma unroll
        for (int i = 0; i < 4; ++i)
            af[i] = *(const bf16x8*)&Asm[cur][(wm * 64 + i * 16 + m) * 32 + quad * 8];
        #pragma unroll
        for (int j = 0; j < 4; ++j)
            bf[j] = *(const bf16x8*)&Bsm[cur][(wn * 64 + j * 16 + m) * 32 + quad * 8];
        #pragma unroll
        for (int i = 0; i < 4; ++i)
            #pragma unroll
            for (int j = 0; j < 4; ++j)
                acc[i][j] = __builtin_amdgcn_mfma_f32_16x16x32_bf16(
                    af[i], bf[j], acc[i][j], 0, 0, 0);

        __syncthreads();
    }

    float bbv[4];
    #pragma unroll
    for (int j = 0; j < 4; ++j)
        bbv[j] = bp[n0 + wn * 64 + j * 16 + m];

    #pragma unroll
    for (int i = 0; i < 4; ++i)
        #pragma unroll
        for (int j = 0; j < 4; ++j)
            #pragma unroll
            for (int r = 0; r < 4; ++r)
                C[(size_t)(m0 + wm * 64 + i * 16 + quad * 4 + r) * Ev
                  + n0 + wn * 64 + j * 16 + m] = acc[i][j][r] + bbv[j];
}

// ---------------------------------------------------------------------------
// ws layout (ushort units): Q 8.4M | K 8.4M | Vt 8.4M | O 8.4M | Wpb 1M
// ---------------------------------------------------------------------------
extern "C" void kernel_launch(void* const* d_in, const int* in_sizes, int n_in,
                              void* d_out, int out_size, void* d_ws, size_t ws_size,
                              hipStream_t stream) {
    const float* x  = (const float*)d_in[0];
    const float* Wk = (const float*)d_in[1];
    const float* Wq = (const float*)d_in[2];
    const float* Wv = (const float*)d_in[3];
    const float* Wp = (const float*)d_in[4];
    const float* bp = (const float*)d_in[5];
    float* out = (float*)d_out;

    ushort* Q   = (ushort*)d_ws;
    ushort* K   = Q   + 8388608;
    ushort* Vt  = K   + 8388608;
    ushort* O   = Vt  + 8388608;
    ushort* Wpb = O   + 8388608;

    qkv_kernel<<<2731, 192, 0, stream>>>(x, Wq, Wk, Wv, Wp, Wpb, Q, K, Vt);
    attn_kernel<<<512, 256, 0, stream>>>(Q, K, Vt, O);
    proj_kernel<<<dim3(64, 8), 256, 0, stream>>>(O, Wpb, bp, out);
}